// Round 10
// baseline (639.249 us; speedup 1.0000x reference)
//
#include <hip/hip_runtime.h>
#include <math.h>

#define Hd 1024
#define Td 64
#define Vd 32000

// ---- static workspace float offsets ----
static const size_t OFF_GENC  = 131072;    // 64*4096
static const size_t OFF_GDEC  = 393216;    // 64*4096
static const size_t OFF_BSE   = 655360;    // 4096
static const size_t OFF_BSD   = 659456;    // 4096
static const size_t OFF_TEN   = 663552;    // 32
static const size_t OFF_MB    = 730144;    // mailbox: 130*1024 + 256 float2 pairs
static const size_t OFF_ST2   = 1000000;   // 64 t x 125 blocks x 4 stats floats

#define MB_H_PAIRS  133120u       // 130 slots x 1024 pairs
#define MB_PAIRS    133376u       // + 256 latent pairs
#define FLAGB       0x3f800000u

__device__ __forceinline__ float fsigm(float x) {
  return __fdividef(1.f, 1.f + __expf(-x));
}
__device__ __forceinline__ float ftanh(float x) {
  return 1.f - __fdividef(2.f, __expf(2.f * x) + 1.f);
}

// PROVEN transport: flagged store + sc0 sc1 poll
__device__ __forceinline__ void st_flag(unsigned long long* p, float v) {
  unsigned long long u = 0x3f80000000000000ull | (unsigned long long)__float_as_uint(v);
  __hip_atomic_store(p, u, __ATOMIC_RELAXED, __HIP_MEMORY_SCOPE_AGENT);
}

__device__ __forceinline__ float4 poll16(const float2* p) {
  float4 a;
  for (;;) {
    asm volatile("global_load_dwordx4 %0, %1, off sc0 sc1\n\ts_waitcnt vmcnt(0)"
                 : "=&v"(a) : "v"(p) : "memory");
    if (__float_as_uint(a.y) == FLAGB && __float_as_uint(a.w) == FLAGB) return a;
  }
}

__device__ __forceinline__ void stage1024(const float2* base, float* dst, int tid) {
  float4 a = poll16(base + 2 * tid);
  ((float2*)dst)[tid] = make_float2(a.x, a.z);
  __syncthreads();
}

// ---------------- prep: bias sums, tense row, mailbox init ------------------
__global__ void prep_kernel(const int* __restrict__ tense,
                            const float* __restrict__ tense_emb,
                            const float* __restrict__ enc_bih, const float* __restrict__ enc_bhh,
                            const float* __restrict__ dec_bih, const float* __restrict__ dec_bhh,
                            float* __restrict__ ws) {
  int gid = blockIdx.x * blockDim.x + threadIdx.x;
  int gsz = gridDim.x * blockDim.x;
  int tens = tense[0];
  for (int i = gid; i < 4096; i += gsz) {
    ws[OFF_BSE + i] = enc_bih[i] + enc_bhh[i];
    ws[OFF_BSD + i] = dec_bih[i] + dec_bhh[i];
  }
  for (int i = gid; i < 32; i += gsz) ws[OFF_TEN + i] = tense_emb[tens * 32 + i];
  float2* mb = (float2*)(ws + OFF_MB);
  for (int i = gid; i < (int)MB_PAIRS; i += gsz) {
    float2 v;
    if (i < (int)MB_H_PAIRS && (i >> 10) == 0) {
      int j = i & 1023;
      v.x = (j < Hd - 32) ? 0.f : tense_emb[tens * 32 + (j - (Hd - 32))];
      v.y = 1.0f;
    } else { v.x = 0.f; v.y = 0.f; }
    mb[i] = v;
  }
}

// ---------------- input-side GEMM with fused gather (R9-proven) -------------
__device__ __forceinline__ void gemm_gather_body(const float* __restrict__ W,
                                                 const float* __restrict__ emb,
                                                 const int* __restrict__ word, int dec_mode,
                                                 const float* __restrict__ bias,
                                                 float* __restrict__ out, int R, int rbase) {
  __shared__ float xs[64][68];
  __shared__ float wsh[64][68];
  const int tid = threadIdx.x;
  const int a = tid >> 4;
  const int b = tid & 15;
  const int sr = tid & 63;
  const int kq = (tid >> 6) << 4;
  const int tok = dec_mode ? ((sr == 0) ? 0 : word[sr - 1]) : word[sr];
  const float* xrow = emb + (size_t)tok * 1024;
  float acc[4][4];
#pragma unroll
  for (int i = 0; i < 4; ++i)
#pragma unroll
    for (int q = 0; q < 4; ++q) acc[i][q] = 0.f;

  for (int kc = 0; kc < 1024; kc += 64) {
    const float4* gx = (const float4*)(xrow + kc + kq);
    const float4* gw = (const float4*)(W + (size_t)(rbase + sr) * 1024 + kc + kq);
    float4 vx0 = gx[0], vx1 = gx[1], vx2 = gx[2], vx3 = gx[3];
    float4 vw0 = gw[0], vw1 = gw[1], vw2 = gw[2], vw3 = gw[3];
    if (dec_mode) {
      vx0.x = fmaxf(vx0.x, 0.f); vx0.y = fmaxf(vx0.y, 0.f); vx0.z = fmaxf(vx0.z, 0.f); vx0.w = fmaxf(vx0.w, 0.f);
      vx1.x = fmaxf(vx1.x, 0.f); vx1.y = fmaxf(vx1.y, 0.f); vx1.z = fmaxf(vx1.z, 0.f); vx1.w = fmaxf(vx1.w, 0.f);
      vx2.x = fmaxf(vx2.x, 0.f); vx2.y = fmaxf(vx2.y, 0.f); vx2.z = fmaxf(vx2.z, 0.f); vx2.w = fmaxf(vx2.w, 0.f);
      vx3.x = fmaxf(vx3.x, 0.f); vx3.y = fmaxf(vx3.y, 0.f); vx3.z = fmaxf(vx3.z, 0.f); vx3.w = fmaxf(vx3.w, 0.f);
    }
    __syncthreads();
    xs[kq +  0][sr] = vx0.x; xs[kq +  1][sr] = vx0.y; xs[kq +  2][sr] = vx0.z; xs[kq +  3][sr] = vx0.w;
    xs[kq +  4][sr] = vx1.x; xs[kq +  5][sr] = vx1.y; xs[kq +  6][sr] = vx1.z; xs[kq +  7][sr] = vx1.w;
    xs[kq +  8][sr] = vx2.x; xs[kq +  9][sr] = vx2.y; xs[kq + 10][sr] = vx2.z; xs[kq + 11][sr] = vx2.w;
    xs[kq + 12][sr] = vx3.x; xs[kq + 13][sr] = vx3.y; xs[kq + 14][sr] = vx3.z; xs[kq + 15][sr] = vx3.w;
    wsh[kq +  0][sr] = vw0.x; wsh[kq +  1][sr] = vw0.y; wsh[kq +  2][sr] = vw0.z; wsh[kq +  3][sr] = vw0.w;
    wsh[kq +  4][sr] = vw1.x; wsh[kq +  5][sr] = vw1.y; wsh[kq +  6][sr] = vw1.z; wsh[kq +  7][sr] = vw1.w;
    wsh[kq +  8][sr] = vw2.x; wsh[kq +  9][sr] = vw2.y; wsh[kq + 10][sr] = vw2.z; wsh[kq + 11][sr] = vw2.w;
    wsh[kq + 12][sr] = vw3.x; wsh[kq + 13][sr] = vw3.y; wsh[kq + 14][sr] = vw3.z; wsh[kq + 15][sr] = vw3.w;
    __syncthreads();
#pragma unroll 8
    for (int kk = 0; kk < 64; ++kk) {
      float4 xv = *(const float4*)&xs[kk][a * 4];
      float4 wv = *(const float4*)&wsh[kk][b * 4];
      acc[0][0] = fmaf(xv.x, wv.x, acc[0][0]); acc[0][1] = fmaf(xv.x, wv.y, acc[0][1]);
      acc[0][2] = fmaf(xv.x, wv.z, acc[0][2]); acc[0][3] = fmaf(xv.x, wv.w, acc[0][3]);
      acc[1][0] = fmaf(xv.y, wv.x, acc[1][0]); acc[1][1] = fmaf(xv.y, wv.y, acc[1][1]);
      acc[1][2] = fmaf(xv.y, wv.z, acc[1][2]); acc[1][3] = fmaf(xv.y, wv.w, acc[1][3]);
      acc[2][0] = fmaf(xv.z, wv.x, acc[2][0]); acc[2][1] = fmaf(xv.z, wv.y, acc[2][1]);
      acc[2][2] = fmaf(xv.z, wv.z, acc[2][2]); acc[2][3] = fmaf(xv.z, wv.w, acc[2][3]);
      acc[3][0] = fmaf(xv.w, wv.x, acc[3][0]); acc[3][1] = fmaf(xv.w, wv.y, acc[3][1]);
      acc[3][2] = fmaf(xv.w, wv.z, acc[3][2]); acc[3][3] = fmaf(xv.w, wv.w, acc[3][3]);
    }
  }
  const int rb = rbase + b * 4;
  float4 bv = *(const float4*)(bias + rb);
#pragma unroll
  for (int i = 0; i < 4; ++i) {
    int t = a * 4 + i;
    float4 o;
    o.x = acc[i][0] + bv.x; o.y = acc[i][1] + bv.y;
    o.z = acc[i][2] + bv.z; o.w = acc[i][3] + bv.w;
    *(float4*)(out + (size_t)t * R + rb) = o;
  }
}

__global__ __launch_bounds__(256, 2) void gemm_dual_kernel(
    const float* __restrict__ enc_emb, const float* __restrict__ dec_emb,
    const int* __restrict__ word,
    const float* __restrict__ W0, const float* __restrict__ b0, float* __restrict__ o0,
    const float* __restrict__ W1, const float* __restrict__ b1, float* __restrict__ o1) {
  if (blockIdx.x < 64)
    gemm_gather_body(W0, enc_emb, word, 0, b0, o0, 4096, blockIdx.x * 64);
  else
    gemm_gather_body(W1, dec_emb, word, 1, b1, o1, 4096, (blockIdx.x - 64) * 64);
}

// 16 scalar weight loads (stride 256B) via one opaque asm block
__device__ __forceinline__ void gload16(const float* base, float* d) {
  asm volatile(
      "global_load_dword %0, %16, off\n\t"
      "global_load_dword %1, %16, off offset:256\n\t"
      "global_load_dword %2, %16, off offset:512\n\t"
      "global_load_dword %3, %16, off offset:768\n\t"
      "global_load_dword %4, %16, off offset:1024\n\t"
      "global_load_dword %5, %16, off offset:1280\n\t"
      "global_load_dword %6, %16, off offset:1536\n\t"
      "global_load_dword %7, %16, off offset:1792\n\t"
      "global_load_dword %8, %16, off offset:2048\n\t"
      "global_load_dword %9, %16, off offset:2304\n\t"
      "global_load_dword %10, %16, off offset:2560\n\t"
      "global_load_dword %11, %16, off offset:2816\n\t"
      "global_load_dword %12, %16, off offset:3072\n\t"
      "global_load_dword %13, %16, off offset:3328\n\t"
      "global_load_dword %14, %16, off offset:3584\n\t"
      "global_load_dword %15, %16, off offset:3840\n\t"
      "s_waitcnt vmcnt(0)"
      : "=&v"(d[0]), "=&v"(d[1]), "=&v"(d[2]), "=&v"(d[3]),
        "=&v"(d[4]), "=&v"(d[5]), "=&v"(d[6]), "=&v"(d[7]),
        "=&v"(d[8]), "=&v"(d[9]), "=&v"(d[10]), "=&v"(d[11]),
        "=&v"(d[12]), "=&v"(d[13]), "=&v"(d[14]), "=&v"(d[15])
      : "v"(base));
}

// ============ MEGA KERNEL: seq (blocks 0..127) + logits workers (128..252) ==
// LDS: union of seq (2336 floats) and worker xs[1024][18] + wsh[64][260] = 35072 floats.
__global__ __launch_bounds__(512, 2) void mega_kernel(
    const float* __restrict__ enc_Whh, const float* __restrict__ dec_Whh,
    const float* __restrict__ W_mean, const float* __restrict__ b_mean,
    const float* __restrict__ W_var, const float* __restrict__ b_var,
    const float* __restrict__ W_l2h, const float* __restrict__ b_l2h,
    const float* __restrict__ eps, float* __restrict__ ws, float* __restrict__ dout,
    const float* __restrict__ W_out, const float* __restrict__ b_out) {
  __shared__ float smem[35072];
  const int tid = threadIdx.x;
  const int lane = tid & 63;
  float2* mb = (float2*)(ws + OFF_MB);
  unsigned long long* mbq = (unsigned long long*)(ws + OFF_MB);

  if (blockIdx.x < 128) {
    // =================== seq branch (R9-proven code) ========================
    float* hsbuf0 = smem;
    float* hsbuf1 = smem + 1024;
    float* lat    = smem + 2048;
    const int wid = tid >> 6;
    const int j = blockIdx.x * 8 + wid;
    const float* Genc = ws + OFF_GENC;
    const float* Gdec = ws + OFF_GDEC;

    float we[4][16], wd[4][16];
#pragma unroll
    for (int r = 0; r < 4; ++r) {
      const size_t ro = (size_t)(r * Hd + j) * Hd + lane;
      gload16(enc_Whh + ro, we[r]);
      gload16(dec_Whh + ro, wd[r]);
    }

    // ---- encoder ----
    float c_reg = 0.f;
    float gb0 = Genc[j], gb1 = Genc[1024 + j], gb2 = Genc[2048 + j], gb3 = Genc[3072 + j];
    for (int t = 0; t < Td; ++t) {
      float* hsb = (t & 1) ? hsbuf1 : hsbuf0;
      stage1024(mb + (size_t)t * 1024, hsb, tid);
      const float* hs = hsb;
      float p0 = 0.f, p1 = 0.f, p2 = 0.f, p3 = 0.f;
#pragma unroll
      for (int i = 0; i < 16; ++i) {
        float hv = hs[lane + 64 * i];
        p0 = fmaf(we[0][i], hv, p0);
        p1 = fmaf(we[1][i], hv, p1);
        p2 = fmaf(we[2][i], hv, p2);
        p3 = fmaf(we[3][i], hv, p3);
      }
#pragma unroll
      for (int off = 32; off; off >>= 1) {
        p0 += __shfl_xor(p0, off, 64); p1 += __shfl_xor(p1, off, 64);
        p2 += __shfl_xor(p2, off, 64); p3 += __shfl_xor(p3, off, 64);
      }
      float gi = gb0 + p0, gf = gb1 + p1, gg = gb2 + p2, go = gb3 + p3;
      c_reg = fsigm(gf) * c_reg + fsigm(gi) * ftanh(gg);
      float hval = fsigm(go) * ftanh(c_reg);
      if (lane == 0) st_flag(mbq + (size_t)(t + 1) * 1024 + j, hval);
      if (t + 1 < Td) {
        gb0 = Genc[(t + 1) * 4096 + j];
        gb1 = Genc[(t + 1) * 4096 + 1024 + j];
        gb2 = Genc[(t + 1) * 4096 + 2048 + j];
        gb3 = Genc[(t + 1) * 4096 + 3072 + j];
      }
    }

    // ---- mean/logvar + latent (blocks 0..31) ----
    if (j < 256) {
      stage1024(mb + (size_t)Td * 1024, hsbuf0, tid);
      const float* hs = hsbuf0;
      const float* Wm = W_mean + (size_t)j * Hd;
      const float* Wv = W_var + (size_t)j * Hd;
      float pm = 0.f, pv = 0.f;
#pragma unroll
      for (int i = 0; i < 16; ++i) {
        float hv = hs[lane + 64 * i];
        pm = fmaf(Wm[lane + 64 * i], hv, pm);
        pv = fmaf(Wv[lane + 64 * i], hv, pv);
      }
#pragma unroll
      for (int off = 32; off; off >>= 1) {
        pm += __shfl_xor(pm, off, 64); pv += __shfl_xor(pv, off, 64);
      }
      if (lane == 0) {
        float m = pm + b_mean[j];
        float lv = pv + b_var[j];
        dout[2048064 + j] = m;
        dout[2048320 + j] = lv;
        float latv = m + eps[j] * __expf(0.5f * lv);
        st_flag(mbq + MB_H_PAIRS + j, latv);
      }
    }

    // ---- poll latent, build [latent | tense] ----
    if (tid < 128) {
      float4 a = poll16(mb + MB_H_PAIRS + 2 * tid);
      lat[2 * tid] = a.x; lat[2 * tid + 1] = a.z;
    } else if (tid < 160) {
      lat[256 + (tid - 128)] = ws[OFF_TEN + (tid - 128)];
    }
    __syncthreads();

    // ---- dec_h0 ----
    {
      const float* Wr = W_l2h + (size_t)j * 288;
      float p = fmaf(Wr[lane], lat[lane], 0.f);
      p = fmaf(Wr[lane + 64], lat[lane + 64], p);
      p = fmaf(Wr[lane + 128], lat[lane + 128], p);
      p = fmaf(Wr[lane + 192], lat[lane + 192], p);
      if (lane < 32) p = fmaf(Wr[lane + 256], lat[lane + 256], p);
#pragma unroll
      for (int off = 32; off; off >>= 1) p += __shfl_xor(p, off, 64);
      if (lane == 0) st_flag(mbq + (size_t)65 * 1024 + j, p + b_l2h[j]);
    }
    __syncthreads();

    // ---- decoder (now flags ALL steps incl. t=63 -> slot 129) ----
    c_reg = 0.f;
    gb0 = Gdec[j]; gb1 = Gdec[1024 + j]; gb2 = Gdec[2048 + j]; gb3 = Gdec[3072 + j];
    for (int t = 0; t < Td; ++t) {
      float* hsb = (t & 1) ? hsbuf1 : hsbuf0;
      stage1024(mb + (size_t)(65 + t) * 1024, hsb, tid);
      const float* hs = hsb;
      float p0 = 0.f, p1 = 0.f, p2 = 0.f, p3 = 0.f;
#pragma unroll
      for (int i = 0; i < 16; ++i) {
        float hv = hs[lane + 64 * i];
        p0 = fmaf(wd[0][i], hv, p0);
        p1 = fmaf(wd[1][i], hv, p1);
        p2 = fmaf(wd[2][i], hv, p2);
        p3 = fmaf(wd[3][i], hv, p3);
      }
#pragma unroll
      for (int off = 32; off; off >>= 1) {
        p0 += __shfl_xor(p0, off, 64); p1 += __shfl_xor(p1, off, 64);
        p2 += __shfl_xor(p2, off, 64); p3 += __shfl_xor(p3, off, 64);
      }
      float gi = gb0 + p0, gf = gb1 + p1, gg = gb2 + p2, go = gb3 + p3;
      c_reg = fsigm(gf) * c_reg + fsigm(gi) * ftanh(gg);
      float hval = fsigm(go) * ftanh(c_reg);
      if (lane == 0) st_flag(mbq + (size_t)(66 + t) * 1024 + j, hval);
      if (t + 1 < Td) {
        gb0 = Gdec[(t + 1) * 4096 + j];
        gb1 = Gdec[(t + 1) * 4096 + 1024 + j];
        gb2 = Gdec[(t + 1) * 4096 + 2048 + j];
        gb3 = Gdec[(t + 1) * 4096 + 3072 + j];
      }
    }
  } else if (blockIdx.x < 253) {
    // =================== logits worker branch ===============================
    const int wb = blockIdx.x - 128;     // 0..124
    const int rbase = wb * 256;
    const int a = tid >> 6;              // wave id 0..7 -> rows {2a, 2a+1}
    float* sd = ws + OFF_ST2;
    float* out64 = dout + 64;

    for (int c = 0; c < 4; ++c) {
      // sentinel: wait (with backoff) until last row of chunk starts appearing
      if (tid == 0) {
        const float2* sp = mb + (size_t)(66 + c * 16 + 15) * 1024;
        for (;;) {
          float4 s;
          asm volatile("global_load_dwordx4 %0, %1, off sc0 sc1\n\ts_waitcnt vmcnt(0)"
                       : "=&v"(s) : "v"(sp) : "memory");
          if (__float_as_uint(s.y) == FLAGB && __float_as_uint(s.w) == FLAGB) break;
          __builtin_amdgcn_s_sleep(32);
        }
      }
      __syncthreads();
      // stage x chunk: 16 rows x 1024 into xs[k][row] (each value flag-verified)
      for (int rr = 0; rr < 16; ++rr) {
        float4 aa = poll16(mb + (size_t)(66 + c * 16 + rr) * 1024 + 2 * tid);
        smem[(2 * tid) * 18 + rr] = aa.x;
        smem[(2 * tid + 1) * 18 + rr] = aa.z;
      }
      __syncthreads();

      float acc[2][4];
#pragma unroll
      for (int i = 0; i < 2; ++i)
#pragma unroll
        for (int q = 0; q < 4; ++q) acc[i][q] = 0.f;

      const int rr2 = tid >> 1;          // 0..255
      const int kh = (tid & 1) * 32;     // 0 or 32
      for (int kc = 0; kc < 1024; kc += 64) {
        const float4* gw = (const float4*)(W_out + (size_t)(rbase + rr2) * 1024 + kc + kh);
        float4 w0 = gw[0], w1 = gw[1], w2 = gw[2], w3 = gw[3];
        float4 w4 = gw[4], w5 = gw[5], w6 = gw[6], w7 = gw[7];
        __syncthreads();   // previous wsh tile consumed
        float* wp = smem + 18432;
        wp[(kh + 0) * 260 + rr2] = w0.x; wp[(kh + 1) * 260 + rr2] = w0.y;
        wp[(kh + 2) * 260 + rr2] = w0.z; wp[(kh + 3) * 260 + rr2] = w0.w;
        wp[(kh + 4) * 260 + rr2] = w1.x; wp[(kh + 5) * 260 + rr2] = w1.y;
        wp[(kh + 6) * 260 + rr2] = w1.z; wp[(kh + 7) * 260 + rr2] = w1.w;
        wp[(kh + 8) * 260 + rr2] = w2.x; wp[(kh + 9) * 260 + rr2] = w2.y;
        wp[(kh + 10) * 260 + rr2] = w2.z; wp[(kh + 11) * 260 + rr2] = w2.w;
        wp[(kh + 12) * 260 + rr2] = w3.x; wp[(kh + 13) * 260 + rr2] = w3.y;
        wp[(kh + 14) * 260 + rr2] = w3.z; wp[(kh + 15) * 260 + rr2] = w3.w;
        wp[(kh + 16) * 260 + rr2] = w4.x; wp[(kh + 17) * 260 + rr2] = w4.y;
        wp[(kh + 18) * 260 + rr2] = w4.z; wp[(kh + 19) * 260 + rr2] = w4.w;
        wp[(kh + 20) * 260 + rr2] = w5.x; wp[(kh + 21) * 260 + rr2] = w5.y;
        wp[(kh + 22) * 260 + rr2] = w5.z; wp[(kh + 23) * 260 + rr2] = w5.w;
        wp[(kh + 24) * 260 + rr2] = w6.x; wp[(kh + 25) * 260 + rr2] = w6.y;
        wp[(kh + 26) * 260 + rr2] = w6.z; wp[(kh + 27) * 260 + rr2] = w6.w;
        wp[(kh + 28) * 260 + rr2] = w7.x; wp[(kh + 29) * 260 + rr2] = w7.y;
        wp[(kh + 30) * 260 + rr2] = w7.z; wp[(kh + 31) * 260 + rr2] = w7.w;
        __syncthreads();
#pragma unroll 8
        for (int kk = 0; kk < 64; ++kk) {
          float2 xv = *(const float2*)&smem[(kc + kk) * 18 + 2 * a];
          float4 wv = *(const float4*)&smem[18432 + kk * 260 + 4 * lane];
          acc[0][0] = fmaf(xv.x, wv.x, acc[0][0]); acc[0][1] = fmaf(xv.x, wv.y, acc[0][1]);
          acc[0][2] = fmaf(xv.x, wv.z, acc[0][2]); acc[0][3] = fmaf(xv.x, wv.w, acc[0][3]);
          acc[1][0] = fmaf(xv.y, wv.x, acc[1][0]); acc[1][1] = fmaf(xv.y, wv.y, acc[1][1]);
          acc[1][2] = fmaf(xv.y, wv.z, acc[1][2]); acc[1][3] = fmaf(xv.y, wv.w, acc[1][3]);
        }
      }
      __syncthreads();   // wsh consumed before next chunk's stage overwrites xs

      // epilogue: bias, store, per-row stats (2 rows per wave)
      const int r0 = rbase + 4 * lane;
      float4 bo = *(const float4*)(b_out + r0);
#pragma unroll
      for (int i = 0; i < 2; ++i) {
        const int t = c * 16 + 2 * a + i;
        float4 o;
        o.x = acc[i][0] + bo.x; o.y = acc[i][1] + bo.y;
        o.z = acc[i][2] + bo.z; o.w = acc[i][3] + bo.w;
        *(float4*)(out64 + (size_t)t * Vd + r0) = o;
        // wave-level max/argmax over 256 cols
        float m = o.x; int mi = r0;
        if (o.y > m) { m = o.y; mi = r0 + 1; }
        if (o.z > m) { m = o.z; mi = r0 + 2; }
        if (o.w > m) { m = o.w; mi = r0 + 3; }
#pragma unroll
        for (int off = 32; off; off >>= 1) {
          float om = __shfl_xor(m, off, 64);
          int oi = __shfl_xor(mi, off, 64);
          if (om > m || (om == m && oi < mi)) { m = om; mi = oi; }
        }
        float s = __expf(o.x - m) + __expf(o.y - m) + __expf(o.z - m) + __expf(o.w - m);
#pragma unroll
        for (int off = 32; off; off >>= 1) s += __shfl_xor(s, off, 64);
        if (lane == 0) {
          sd[(size_t)(t * 125 + wb) * 4 + 0] = m;
          sd[(size_t)(t * 125 + wb) * 4 + 1] = (float)mi;
          sd[(size_t)(t * 125 + wb) * 4 + 2] = s;
        }
      }
    }
  }
}

// ---------------- combine 125 partials + normalize quarter-row ---------------
__global__ __launch_bounds__(256) void lfin_kernel(float* __restrict__ out,
                                                   const float* __restrict__ sd) {
  const int blk = blockIdx.x, t = blk >> 2, q = blk & 3, tid = threadIdx.x;
  float M = -INFINITY;
  for (int k = 0; k < 125; ++k) M = fmaxf(M, sd[(size_t)(t * 125 + k) * 4]);
  float S = 0.f;
  for (int k = 0; k < 125; ++k)
    S += sd[(size_t)(t * 125 + k) * 4 + 2] * __expf(sd[(size_t)(t * 125 + k) * 4] - M);
  float corr = M + logf(S);
  float4* r4 = (float4*)(out + 64 + (size_t)t * Vd + q * 8000);
  for (int i = tid; i < 2000; i += 256) {
    float4 v = r4[i];
    v.x -= corr; v.y -= corr; v.z -= corr; v.w -= corr;
    r4[i] = v;
  }
  if (q == 0 && tid == 0) {
    float bm = -INFINITY; int bi = 0;
    for (int k = 0; k < 125; ++k) {
      float m = sd[(size_t)(t * 125 + k) * 4];
      if (m > bm) { bm = m; bi = (int)sd[(size_t)(t * 125 + k) * 4 + 1]; }
    }
    out[t] = (float)bi;
  }
}

extern "C" void kernel_launch(void* const* d_in, const int* in_sizes, int n_in,
                              void* d_out, int out_size, void* d_ws, size_t ws_size,
                              hipStream_t stream) {
  (void)in_sizes; (void)n_in; (void)out_size; (void)ws_size;
  const int* word       = (const int*)d_in[0];
  const int* tense      = (const int*)d_in[1];
  const float* tense_emb = (const float*)d_in[3];
  const float* enc_emb   = (const float*)d_in[4];
  const float* enc_Wih   = (const float*)d_in[5];
  const float* enc_Whh   = (const float*)d_in[6];
  const float* enc_bih   = (const float*)d_in[7];
  const float* enc_bhh   = (const float*)d_in[8];
  const float* W_mean    = (const float*)d_in[9];
  const float* b_mean    = (const float*)d_in[10];
  const float* W_var     = (const float*)d_in[11];
  const float* b_var     = (const float*)d_in[12];
  const float* W_l2h     = (const float*)d_in[13];
  const float* b_l2h     = (const float*)d_in[14];
  const float* dec_emb   = (const float*)d_in[15];
  const float* dec_Wih   = (const float*)d_in[16];
  const float* dec_Whh   = (const float*)d_in[17];
  const float* dec_bih   = (const float*)d_in[18];
  const float* dec_bhh   = (const float*)d_in[19];
  const float* W_out     = (const float*)d_in[20];
  const float* b_out     = (const float*)d_in[21];
  const float* eps       = (const float*)d_in[22];
  float* out = (float*)d_out;
  float* ws  = (float*)d_ws;

  prep_kernel<<<256, 256, 0, stream>>>(tense, tense_emb, enc_bih, enc_bhh,
                                       dec_bih, dec_bhh, ws);
  gemm_dual_kernel<<<128, 256, 0, stream>>>(enc_emb, dec_emb, word,
                                            enc_Wih, ws + OFF_BSE, ws + OFF_GENC,
                                            dec_Wih, ws + OFF_BSD, ws + OFF_GDEC);
  // 253 blocks, 140KB LDS => 1 block/CU, 253 <= 256 CUs => all co-resident (deadlock-free)
  mega_kernel<<<253, 512, 0, stream>>>(enc_Whh, dec_Whh, W_mean, b_mean, W_var, b_var,
                                       W_l2h, b_l2h, eps, ws, out, W_out, b_out);
  lfin_kernel<<<256, 256, 0, stream>>>(out, ws + OFF_ST2);
}

// Round 11
// 508.601 us; speedup vs baseline: 1.2569x; 1.2569x over previous
//
#include <hip/hip_runtime.h>
#include <math.h>

#define Hd 1024
#define Td 64
#define Vd 32000

// ---- static workspace float offsets ----
static const size_t OFF_GENC  = 131072;    // 64*4096
static const size_t OFF_GDEC  = 393216;    // 64*4096
static const size_t OFF_TEN   = 663552;    // 32
static const size_t OFF_HALL  = 663584;    // 64*1024 (ends 729120)
static const size_t OFF_MB    = 730144;    // mailbox: 130*1024 + 256 float2 pairs
static const size_t OFF_ST2   = 1000000;   // 64 t x 500 blocks x 4 stats floats

#define MB_H_PAIRS  133120u       // 130 slots x 1024 pairs
#define MB_PAIRS    133376u       // + 256 latent pairs
#define FLAGB       0x3f800000u

__device__ __forceinline__ float fsigm(float x) {
  return __fdividef(1.f, 1.f + __expf(-x));
}
__device__ __forceinline__ float ftanh(float x) {
  return 1.f - __fdividef(2.f, __expf(2.f * x) + 1.f);
}

// PROVEN transport (R3-R9): flagged store + sc0 sc1 poll
__device__ __forceinline__ void st_flag(unsigned long long* p, float v) {
  unsigned long long u = 0x3f80000000000000ull | (unsigned long long)__float_as_uint(v);
  __hip_atomic_store(p, u, __ATOMIC_RELAXED, __HIP_MEMORY_SCOPE_AGENT);
}

__device__ __forceinline__ float4 poll16(const float2* p) {
  float4 a;
  for (;;) {
    asm volatile("global_load_dwordx4 %0, %1, off sc0 sc1\n\ts_waitcnt vmcnt(0)"
                 : "=&v"(a) : "v"(p) : "memory");
    if (__float_as_uint(a.y) == FLAGB && __float_as_uint(a.w) == FLAGB) return a;
  }
}

__device__ __forceinline__ void stage1024(const float2* base, float* dst, int tid) {
  float4 a = poll16(base + 2 * tid);
  ((float2*)dst)[tid] = make_float2(a.x, a.z);
  __syncthreads();
}

// ---------------- input-side GEMM with fused gather + dual-bias epilogue ----
__device__ __forceinline__ void gemm_gather_body(const float* __restrict__ W,
                                                 const float* __restrict__ emb,
                                                 const int* __restrict__ word, int dec_mode,
                                                 const float* __restrict__ bih,
                                                 const float* __restrict__ bhh,
                                                 float* __restrict__ out, int R, int rbase) {
  __shared__ float xs[64][68];
  __shared__ float wsh[64][68];
  const int tid = threadIdx.x;
  const int a = tid >> 4;
  const int b = tid & 15;
  const int sr = tid & 63;
  const int kq = (tid >> 6) << 4;
  const int tok = dec_mode ? ((sr == 0) ? 0 : word[sr - 1]) : word[sr];
  const float* xrow = emb + (size_t)tok * 1024;
  float acc[4][4];
#pragma unroll
  for (int i = 0; i < 4; ++i)
#pragma unroll
    for (int q = 0; q < 4; ++q) acc[i][q] = 0.f;

  for (int kc = 0; kc < 1024; kc += 64) {
    const float4* gx = (const float4*)(xrow + kc + kq);
    const float4* gw = (const float4*)(W + (size_t)(rbase + sr) * 1024 + kc + kq);
    float4 vx0 = gx[0], vx1 = gx[1], vx2 = gx[2], vx3 = gx[3];
    float4 vw0 = gw[0], vw1 = gw[1], vw2 = gw[2], vw3 = gw[3];
    if (dec_mode) {
      vx0.x = fmaxf(vx0.x, 0.f); vx0.y = fmaxf(vx0.y, 0.f); vx0.z = fmaxf(vx0.z, 0.f); vx0.w = fmaxf(vx0.w, 0.f);
      vx1.x = fmaxf(vx1.x, 0.f); vx1.y = fmaxf(vx1.y, 0.f); vx1.z = fmaxf(vx1.z, 0.f); vx1.w = fmaxf(vx1.w, 0.f);
      vx2.x = fmaxf(vx2.x, 0.f); vx2.y = fmaxf(vx2.y, 0.f); vx2.z = fmaxf(vx2.z, 0.f); vx2.w = fmaxf(vx2.w, 0.f);
      vx3.x = fmaxf(vx3.x, 0.f); vx3.y = fmaxf(vx3.y, 0.f); vx3.z = fmaxf(vx3.z, 0.f); vx3.w = fmaxf(vx3.w, 0.f);
    }
    __syncthreads();
    xs[kq +  0][sr] = vx0.x; xs[kq +  1][sr] = vx0.y; xs[kq +  2][sr] = vx0.z; xs[kq +  3][sr] = vx0.w;
    xs[kq +  4][sr] = vx1.x; xs[kq +  5][sr] = vx1.y; xs[kq +  6][sr] = vx1.z; xs[kq +  7][sr] = vx1.w;
    xs[kq +  8][sr] = vx2.x; xs[kq +  9][sr] = vx2.y; xs[kq + 10][sr] = vx2.z; xs[kq + 11][sr] = vx2.w;
    xs[kq + 12][sr] = vx3.x; xs[kq + 13][sr] = vx3.y; xs[kq + 14][sr] = vx3.z; xs[kq + 15][sr] = vx3.w;
    wsh[kq +  0][sr] = vw0.x; wsh[kq +  1][sr] = vw0.y; wsh[kq +  2][sr] = vw0.z; wsh[kq +  3][sr] = vw0.w;
    wsh[kq +  4][sr] = vw1.x; wsh[kq +  5][sr] = vw1.y; wsh[kq +  6][sr] = vw1.z; wsh[kq +  7][sr] = vw1.w;
    wsh[kq +  8][sr] = vw2.x; wsh[kq +  9][sr] = vw2.y; wsh[kq + 10][sr] = vw2.z; wsh[kq + 11][sr] = vw2.w;
    wsh[kq + 12][sr] = vw3.x; wsh[kq + 13][sr] = vw3.y; wsh[kq + 14][sr] = vw3.z; wsh[kq + 15][sr] = vw3.w;
    __syncthreads();
#pragma unroll 8
    for (int kk = 0; kk < 64; ++kk) {
      float4 xv = *(const float4*)&xs[kk][a * 4];
      float4 wv = *(const float4*)&wsh[kk][b * 4];
      acc[0][0] = fmaf(xv.x, wv.x, acc[0][0]); acc[0][1] = fmaf(xv.x, wv.y, acc[0][1]);
      acc[0][2] = fmaf(xv.x, wv.z, acc[0][2]); acc[0][3] = fmaf(xv.x, wv.w, acc[0][3]);
      acc[1][0] = fmaf(xv.y, wv.x, acc[1][0]); acc[1][1] = fmaf(xv.y, wv.y, acc[1][1]);
      acc[1][2] = fmaf(xv.y, wv.z, acc[1][2]); acc[1][3] = fmaf(xv.y, wv.w, acc[1][3]);
      acc[2][0] = fmaf(xv.z, wv.x, acc[2][0]); acc[2][1] = fmaf(xv.z, wv.y, acc[2][1]);
      acc[2][2] = fmaf(xv.z, wv.z, acc[2][2]); acc[2][3] = fmaf(xv.z, wv.w, acc[2][3]);
      acc[3][0] = fmaf(xv.w, wv.x, acc[3][0]); acc[3][1] = fmaf(xv.w, wv.y, acc[3][1]);
      acc[3][2] = fmaf(xv.w, wv.z, acc[3][2]); acc[3][3] = fmaf(xv.w, wv.w, acc[3][3]);
    }
  }
  const int rb = rbase + b * 4;
  float4 b1 = *(const float4*)(bih + rb);
  float4 b2 = *(const float4*)(bhh + rb);
#pragma unroll
  for (int i = 0; i < 4; ++i) {
    int t = a * 4 + i;
    float4 o;
    o.x = acc[i][0] + b1.x + b2.x; o.y = acc[i][1] + b1.y + b2.y;
    o.z = acc[i][2] + b1.z + b2.z; o.w = acc[i][3] + b1.w + b2.w;
    *(float4*)(out + (size_t)t * R + rb) = o;
  }
}

// gemm_dual + mailbox/tense init (replaces prep_kernel)
__global__ __launch_bounds__(256, 2) void gemm_dual_kernel(
    const int* __restrict__ tense, const float* __restrict__ tense_emb,
    const float* __restrict__ enc_emb, const float* __restrict__ dec_emb,
    const int* __restrict__ word,
    const float* __restrict__ W0, const float* __restrict__ bih0,
    const float* __restrict__ bhh0, float* __restrict__ o0,
    const float* __restrict__ W1, const float* __restrict__ bih1,
    const float* __restrict__ bhh1, float* __restrict__ o1,
    float* __restrict__ ws) {
  // distributed init (no intra-block dependency with the GEMM below)
  {
    int gid = blockIdx.x * blockDim.x + threadIdx.x;
    int gsz = gridDim.x * blockDim.x;
    int tens = tense[0];
    if (gid < 32) ws[OFF_TEN + gid] = tense_emb[tens * 32 + gid];
    float2* mb = (float2*)(ws + OFF_MB);
    for (int i = gid; i < (int)MB_PAIRS; i += gsz) {
      float2 v;
      if (i < (int)MB_H_PAIRS && (i >> 10) == 0) {
        int j = i & 1023;
        v.x = (j < Hd - 32) ? 0.f : tense_emb[tens * 32 + (j - (Hd - 32))];
        v.y = 1.0f;
      } else { v.x = 0.f; v.y = 0.f; }
      mb[i] = v;
    }
  }
  if (blockIdx.x < 64)
    gemm_gather_body(W0, enc_emb, word, 0, bih0, bhh0, o0, 4096, blockIdx.x * 64);
  else
    gemm_gather_body(W1, dec_emb, word, 1, bih1, bhh1, o1, 4096, (blockIdx.x - 64) * 64);
}

// ---------------- W_out GEMM with fused per-row partial stats ---------------
// R9-proven body; epilogue adds online {max, argmax, sumexp} over the block's
// 64 cols per t-row via 16-lane shuffle merge -> sd[t*500 + blk].
__global__ __launch_bounds__(256, 2) void gemm_kernel(const float* __restrict__ W,
                                                      const float* __restrict__ x,
                                                      const float* __restrict__ bias,
                                                      float* __restrict__ out, int R,
                                                      float* __restrict__ sd) {
  __shared__ float xs[64][68];
  __shared__ float wsh[64][68];
  const int tid = threadIdx.x;
  const int a = tid >> 4;
  const int b = tid & 15;
  const int sr = tid & 63;
  const int kq = (tid >> 6) << 4;
  const int rbase = blockIdx.x * 64;
  float acc[4][4];
#pragma unroll
  for (int i = 0; i < 4; ++i)
#pragma unroll
    for (int q = 0; q < 4; ++q) acc[i][q] = 0.f;

  for (int kc = 0; kc < 1024; kc += 64) {
    const float4* gx = (const float4*)(x + (size_t)sr * 1024 + kc + kq);
    const float4* gw = (const float4*)(W + (size_t)(rbase + sr) * 1024 + kc + kq);
    float4 vx0 = gx[0], vx1 = gx[1], vx2 = gx[2], vx3 = gx[3];
    float4 vw0 = gw[0], vw1 = gw[1], vw2 = gw[2], vw3 = gw[3];
    __syncthreads();
    xs[kq +  0][sr] = vx0.x; xs[kq +  1][sr] = vx0.y; xs[kq +  2][sr] = vx0.z; xs[kq +  3][sr] = vx0.w;
    xs[kq +  4][sr] = vx1.x; xs[kq +  5][sr] = vx1.y; xs[kq +  6][sr] = vx1.z; xs[kq +  7][sr] = vx1.w;
    xs[kq +  8][sr] = vx2.x; xs[kq +  9][sr] = vx2.y; xs[kq + 10][sr] = vx2.z; xs[kq + 11][sr] = vx2.w;
    xs[kq + 12][sr] = vx3.x; xs[kq + 13][sr] = vx3.y; xs[kq + 14][sr] = vx3.z; xs[kq + 15][sr] = vx3.w;
    wsh[kq +  0][sr] = vw0.x; wsh[kq +  1][sr] = vw0.y; wsh[kq +  2][sr] = vw0.z; wsh[kq +  3][sr] = vw0.w;
    wsh[kq +  4][sr] = vw1.x; wsh[kq +  5][sr] = vw1.y; wsh[kq +  6][sr] = vw1.z; wsh[kq +  7][sr] = vw1.w;
    wsh[kq +  8][sr] = vw2.x; wsh[kq +  9][sr] = vw2.y; wsh[kq + 10][sr] = vw2.z; wsh[kq + 11][sr] = vw2.w;
    wsh[kq + 12][sr] = vw3.x; wsh[kq + 13][sr] = vw3.y; wsh[kq + 14][sr] = vw3.z; wsh[kq + 15][sr] = vw3.w;
    __syncthreads();
#pragma unroll 8
    for (int kk = 0; kk < 64; ++kk) {
      float4 xv = *(const float4*)&xs[kk][a * 4];
      float4 wv = *(const float4*)&wsh[kk][b * 4];
      acc[0][0] = fmaf(xv.x, wv.x, acc[0][0]); acc[0][1] = fmaf(xv.x, wv.y, acc[0][1]);
      acc[0][2] = fmaf(xv.x, wv.z, acc[0][2]); acc[0][3] = fmaf(xv.x, wv.w, acc[0][3]);
      acc[1][0] = fmaf(xv.y, wv.x, acc[1][0]); acc[1][1] = fmaf(xv.y, wv.y, acc[1][1]);
      acc[1][2] = fmaf(xv.y, wv.z, acc[1][2]); acc[1][3] = fmaf(xv.y, wv.w, acc[1][3]);
      acc[2][0] = fmaf(xv.z, wv.x, acc[2][0]); acc[2][1] = fmaf(xv.z, wv.y, acc[2][1]);
      acc[2][2] = fmaf(xv.z, wv.z, acc[2][2]); acc[2][3] = fmaf(xv.z, wv.w, acc[2][3]);
      acc[3][0] = fmaf(xv.w, wv.x, acc[3][0]); acc[3][1] = fmaf(xv.w, wv.y, acc[3][1]);
      acc[3][2] = fmaf(xv.w, wv.z, acc[3][2]); acc[3][3] = fmaf(xv.w, wv.w, acc[3][3]);
    }
  }
  const int rb = rbase + b * 4;
  float4 bv = *(const float4*)(bias + rb);
#pragma unroll
  for (int i = 0; i < 4; ++i) {
    int t = a * 4 + i;
    float4 o;
    o.x = acc[i][0] + bv.x; o.y = acc[i][1] + bv.y;
    o.z = acc[i][2] + bv.z; o.w = acc[i][3] + bv.w;
    *(float4*)(out + (size_t)t * R + rb) = o;
    // ---- per-row partial stats over this block's 64 cols ----
    float m = o.x; int mi = rb;
    if (o.y > m) { m = o.y; mi = rb + 1; }
    if (o.z > m) { m = o.z; mi = rb + 2; }
    if (o.w > m) { m = o.w; mi = rb + 3; }
    float s = __expf(o.x - m) + __expf(o.y - m) + __expf(o.z - m) + __expf(o.w - m);
#pragma unroll
    for (int off = 1; off < 16; off <<= 1) {
      float om = __shfl_xor(m, off, 64);
      int   oi = __shfl_xor(mi, off, 64);
      float os = __shfl_xor(s, off, 64);
      if (om > m || (om == m && oi < mi)) {
        s = os + s * __expf(m - om);
        m = om; mi = oi;
      } else {
        s = s + os * __expf(om - m);
      }
    }
    if (b == 0) {
      float* p = sd + ((size_t)t * 500 + blockIdx.x) * 4;
      p[0] = m; p[1] = (float)mi; p[2] = s;
    }
  }
}

// 16 scalar weight loads (stride 256B) via one opaque asm block
__device__ __forceinline__ void gload16(const float* base, float* d) {
  asm volatile(
      "global_load_dword %0, %16, off\n\t"
      "global_load_dword %1, %16, off offset:256\n\t"
      "global_load_dword %2, %16, off offset:512\n\t"
      "global_load_dword %3, %16, off offset:768\n\t"
      "global_load_dword %4, %16, off offset:1024\n\t"
      "global_load_dword %5, %16, off offset:1280\n\t"
      "global_load_dword %6, %16, off offset:1536\n\t"
      "global_load_dword %7, %16, off offset:1792\n\t"
      "global_load_dword %8, %16, off offset:2048\n\t"
      "global_load_dword %9, %16, off offset:2304\n\t"
      "global_load_dword %10, %16, off offset:2560\n\t"
      "global_load_dword %11, %16, off offset:2816\n\t"
      "global_load_dword %12, %16, off offset:3072\n\t"
      "global_load_dword %13, %16, off offset:3328\n\t"
      "global_load_dword %14, %16, off offset:3584\n\t"
      "global_load_dword %15, %16, off offset:3840\n\t"
      "s_waitcnt vmcnt(0)"
      : "=&v"(d[0]), "=&v"(d[1]), "=&v"(d[2]), "=&v"(d[3]),
        "=&v"(d[4]), "=&v"(d[5]), "=&v"(d[6]), "=&v"(d[7]),
        "=&v"(d[8]), "=&v"(d[9]), "=&v"(d[10]), "=&v"(d[11]),
        "=&v"(d[12]), "=&v"(d[13]), "=&v"(d[14]), "=&v"(d[15])
      : "v"(base));
}

// ---------------- persistent dataflow sequential kernel (R9-proven) ---------
__global__ __launch_bounds__(512, 2) void seq_kernel(
    const float* __restrict__ enc_Whh, const float* __restrict__ dec_Whh,
    const float* __restrict__ W_mean, const float* __restrict__ b_mean,
    const float* __restrict__ W_var, const float* __restrict__ b_var,
    const float* __restrict__ W_l2h, const float* __restrict__ b_l2h,
    const float* __restrict__ eps, float* __restrict__ ws, float* __restrict__ dout) {
  __shared__ float hsbuf[2][Hd];
  __shared__ float lat[288];
  const int tid = threadIdx.x;
  const int lane = tid & 63;
  const int wid = tid >> 6;
  const int j = blockIdx.x * 8 + wid;          // 0..1023

  float2* mb = (float2*)(ws + OFF_MB);
  unsigned long long* mbq = (unsigned long long*)(ws + OFF_MB);
  const float* Genc = ws + OFF_GENC;
  const float* Gdec = ws + OFF_GDEC;
  float* h_all = ws + OFF_HALL;

  float we[4][16], wd[4][16];
#pragma unroll
  for (int r = 0; r < 4; ++r) {
    const size_t ro = (size_t)(r * Hd + j) * Hd + lane;
    gload16(enc_Whh + ro, we[r]);
    gload16(dec_Whh + ro, wd[r]);
  }

  // ---- encoder ----
  float c_reg = 0.f;
  float gb0 = Genc[j], gb1 = Genc[1024 + j], gb2 = Genc[2048 + j], gb3 = Genc[3072 + j];
  for (int t = 0; t < Td; ++t) {
    stage1024(mb + (size_t)t * 1024, hsbuf[t & 1], tid);
    const float* hs = hsbuf[t & 1];
    float p0 = 0.f, p1 = 0.f, p2 = 0.f, p3 = 0.f;
#pragma unroll
    for (int i = 0; i < 16; ++i) {
      float hv = hs[lane + 64 * i];
      p0 = fmaf(we[0][i], hv, p0);
      p1 = fmaf(we[1][i], hv, p1);
      p2 = fmaf(we[2][i], hv, p2);
      p3 = fmaf(we[3][i], hv, p3);
    }
#pragma unroll
    for (int off = 32; off; off >>= 1) {
      p0 += __shfl_xor(p0, off, 64); p1 += __shfl_xor(p1, off, 64);
      p2 += __shfl_xor(p2, off, 64); p3 += __shfl_xor(p3, off, 64);
    }
    float gi = gb0 + p0, gf = gb1 + p1, gg = gb2 + p2, go = gb3 + p3;
    c_reg = fsigm(gf) * c_reg + fsigm(gi) * ftanh(gg);
    float hval = fsigm(go) * ftanh(c_reg);
    if (lane == 0) st_flag(mbq + (size_t)(t + 1) * 1024 + j, hval);
    if (t + 1 < Td) {
      gb0 = Genc[(t + 1) * 4096 + j];
      gb1 = Genc[(t + 1) * 4096 + 1024 + j];
      gb2 = Genc[(t + 1) * 4096 + 2048 + j];
      gb3 = Genc[(t + 1) * 4096 + 3072 + j];
    }
  }

  // ---- mean/logvar + latent (blocks 0..31) ----
  if (j < 256) {
    stage1024(mb + (size_t)Td * 1024, hsbuf[0], tid);
    const float* hs = hsbuf[0];
    const float* Wm = W_mean + (size_t)j * Hd;
    const float* Wv = W_var + (size_t)j * Hd;
    float pm = 0.f, pv = 0.f;
#pragma unroll
    for (int i = 0; i < 16; ++i) {
      float hv = hs[lane + 64 * i];
      pm = fmaf(Wm[lane + 64 * i], hv, pm);
      pv = fmaf(Wv[lane + 64 * i], hv, pv);
    }
#pragma unroll
    for (int off = 32; off; off >>= 1) {
      pm += __shfl_xor(pm, off, 64); pv += __shfl_xor(pv, off, 64);
    }
    if (lane == 0) {
      float m = pm + b_mean[j];
      float lv = pv + b_var[j];
      dout[2048064 + j] = m;
      dout[2048320 + j] = lv;
      float latv = m + eps[j] * __expf(0.5f * lv);
      st_flag(mbq + MB_H_PAIRS + j, latv);
    }
  }

  // ---- poll latent, build [latent | tense] in LDS ----
  if (tid < 128) {
    float4 a = poll16(mb + MB_H_PAIRS + 2 * tid);
    lat[2 * tid] = a.x; lat[2 * tid + 1] = a.z;
  } else if (tid < 160) {
    lat[256 + (tid - 128)] = ws[OFF_TEN + (tid - 128)];
  }
  __syncthreads();

  // ---- dec_h0[j] = W_l2h[j]·[latent|tense] + b ----
  {
    const float* Wr = W_l2h + (size_t)j * 288;
    float p = fmaf(Wr[lane], lat[lane], 0.f);
    p = fmaf(Wr[lane + 64], lat[lane + 64], p);
    p = fmaf(Wr[lane + 128], lat[lane + 128], p);
    p = fmaf(Wr[lane + 192], lat[lane + 192], p);
    if (lane < 32) p = fmaf(Wr[lane + 256], lat[lane + 256], p);
#pragma unroll
    for (int off = 32; off; off >>= 1) p += __shfl_xor(p, off, 64);
    if (lane == 0) st_flag(mbq + (size_t)65 * 1024 + j, p + b_l2h[j]);
  }
  __syncthreads();

  // ---- decoder ----
  c_reg = 0.f;
  gb0 = Gdec[j]; gb1 = Gdec[1024 + j]; gb2 = Gdec[2048 + j]; gb3 = Gdec[3072 + j];
  for (int t = 0; t < Td; ++t) {
    stage1024(mb + (size_t)(65 + t) * 1024, hsbuf[t & 1], tid);
    const float* hs = hsbuf[t & 1];
    float p0 = 0.f, p1 = 0.f, p2 = 0.f, p3 = 0.f;
#pragma unroll
    for (int i = 0; i < 16; ++i) {
      float hv = hs[lane + 64 * i];
      p0 = fmaf(wd[0][i], hv, p0);
      p1 = fmaf(wd[1][i], hv, p1);
      p2 = fmaf(wd[2][i], hv, p2);
      p3 = fmaf(wd[3][i], hv, p3);
    }
#pragma unroll
    for (int off = 32; off; off >>= 1) {
      p0 += __shfl_xor(p0, off, 64); p1 += __shfl_xor(p1, off, 64);
      p2 += __shfl_xor(p2, off, 64); p3 += __shfl_xor(p3, off, 64);
    }
    float gi = gb0 + p0, gf = gb1 + p1, gg = gb2 + p2, go = gb3 + p3;
    c_reg = fsigm(gf) * c_reg + fsigm(gi) * ftanh(gg);
    float hval = fsigm(go) * ftanh(c_reg);
    if (lane == 0) {
      if (t + 1 < Td) st_flag(mbq + (size_t)(66 + t) * 1024 + j, hval);
      h_all[(size_t)t * Hd + j] = hval;
    }
    if (t + 1 < Td) {
      gb0 = Gdec[(t + 1) * 4096 + j];
      gb1 = Gdec[(t + 1) * 4096 + 1024 + j];
      gb2 = Gdec[(t + 1) * 4096 + 2048 + j];
      gb3 = Gdec[(t + 1) * 4096 + 3072 + j];
    }
  }
}

// ---------------- combine 500 partials + normalize quarter-row ---------------
__global__ __launch_bounds__(256) void lfin_kernel(float* __restrict__ out,
                                                   const float* __restrict__ sd) {
  const int blk = blockIdx.x, t = blk >> 2, q = blk & 3, tid = threadIdx.x;
  __shared__ float sm[256];
  __shared__ float ss[256];
  __shared__ int si[256];
  float M = -INFINITY, S = 0.f; int MI = 0x7fffffff;
  for (int k = tid; k < 500; k += 256) {
    const float* p = sd + ((size_t)t * 500 + k) * 4;
    float m = p[0]; int mi = (int)p[1]; float s = p[2];
    if (m > M || (m == M && mi < MI)) {
      S = s + S * __expf(M - m);
      M = m; MI = mi;
    } else {
      S = S + s * __expf(m - M);
    }
  }
  sm[tid] = M; si[tid] = MI; ss[tid] = S;
  __syncthreads();
  for (int st = 128; st > 0; st >>= 1) {
    if (tid < st) {
      float om = sm[tid + st]; int oi = si[tid + st]; float os = ss[tid + st];
      if (om > sm[tid] || (om == sm[tid] && oi < si[tid])) {
        ss[tid] = os + ss[tid] * __expf(sm[tid] - om);
        sm[tid] = om; si[tid] = oi;
      } else {
        ss[tid] = ss[tid] + os * __expf(om - sm[tid]);
      }
    }
    __syncthreads();
  }
  float corr = sm[0] + logf(ss[0]);
  float4* r4 = (float4*)(out + 64 + (size_t)t * Vd + q * 8000);
  for (int i = tid; i < 2000; i += 256) {
    float4 v = r4[i];
    v.x -= corr; v.y -= corr; v.z -= corr; v.w -= corr;
    r4[i] = v;
  }
  if (q == 0 && tid == 0) out[t] = (float)si[0];
}

extern "C" void kernel_launch(void* const* d_in, const int* in_sizes, int n_in,
                              void* d_out, int out_size, void* d_ws, size_t ws_size,
                              hipStream_t stream) {
  (void)in_sizes; (void)n_in; (void)out_size; (void)ws_size;
  const int* word       = (const int*)d_in[0];
  const int* tense      = (const int*)d_in[1];
  const float* tense_emb = (const float*)d_in[3];
  const float* enc_emb   = (const float*)d_in[4];
  const float* enc_Wih   = (const float*)d_in[5];
  const float* enc_Whh   = (const float*)d_in[6];
  const float* enc_bih   = (const float*)d_in[7];
  const float* enc_bhh   = (const float*)d_in[8];
  const float* W_mean    = (const float*)d_in[9];
  const float* b_mean    = (const float*)d_in[10];
  const float* W_var     = (const float*)d_in[11];
  const float* b_var     = (const float*)d_in[12];
  const float* W_l2h     = (const float*)d_in[13];
  const float* b_l2h     = (const float*)d_in[14];
  const float* dec_emb   = (const float*)d_in[15];
  const float* dec_Wih   = (const float*)d_in[16];
  const float* dec_Whh   = (const float*)d_in[17];
  const float* dec_bih   = (const float*)d_in[18];
  const float* dec_bhh   = (const float*)d_in[19];
  const float* W_out     = (const float*)d_in[20];
  const float* b_out     = (const float*)d_in[21];
  const float* eps       = (const float*)d_in[22];
  float* out = (float*)d_out;
  float* ws  = (float*)d_ws;

  gemm_dual_kernel<<<128, 256, 0, stream>>>(tense, tense_emb, enc_emb, dec_emb, word,
                                            enc_Wih, enc_bih, enc_bhh, ws + OFF_GENC,
                                            dec_Wih, dec_bih, dec_bhh, ws + OFF_GDEC, ws);
  seq_kernel<<<128, 512, 0, stream>>>(enc_Whh, dec_Whh, W_mean, b_mean, W_var, b_var,
                                      W_l2h, b_l2h, eps, ws, out);
  gemm_kernel<<<500, 256, 0, stream>>>(W_out, ws + OFF_HALL, b_out, out + 64, 32000,
                                       ws + OFF_ST2);
  lfin_kernel<<<256, 256, 0, stream>>>(out, ws + OFF_ST2);
}

// Round 12
// 473.603 us; speedup vs baseline: 1.3498x; 1.0739x over previous
//
#include <hip/hip_runtime.h>
#include <math.h>

#define Hd 1024
#define Td 64
#define Vd 32000

// ---- workspace float offsets (re-laid out for split-G) ----
static const size_t OFF_GENC0 = 0;         // 64*4096
static const size_t OFF_GENC1 = 262144;    // 64*4096
static const size_t OFF_GDEC0 = 524288;    // 64*4096
static const size_t OFF_GDEC1 = 786432;    // 64*4096 (ends 1048576)
static const size_t OFF_TEN   = 1048576;   // 32
static const size_t OFF_HALL  = 1048640;   // 64*1024 (ends 1114176)
static const size_t OFF_MB    = 1114176;   // mailbox: 133376 float2 pairs
static const size_t OFF_ST2   = 1380928;   // 64 t x 500 blocks x 4 stats floats

#define MB_H_PAIRS  133120u       // 130 slots x 1024 pairs
#define MB_PAIRS    133376u       // + 256 latent pairs
#define FLAGB       0x3f800000u

__device__ __forceinline__ float fsigm(float x) {
  return __fdividef(1.f, 1.f + __expf(-x));
}
__device__ __forceinline__ float ftanh(float x) {
  return 1.f - __fdividef(2.f, __expf(2.f * x) + 1.f);
}

// PROVEN transport (R3-R11): flagged store + sc0 sc1 poll
__device__ __forceinline__ void st_flag(unsigned long long* p, float v) {
  unsigned long long u = 0x3f80000000000000ull | (unsigned long long)__float_as_uint(v);
  __hip_atomic_store(p, u, __ATOMIC_RELAXED, __HIP_MEMORY_SCOPE_AGENT);
}

__device__ __forceinline__ float4 poll16(const float2* p) {
  float4 a;
  for (;;) {
    asm volatile("global_load_dwordx4 %0, %1, off sc0 sc1\n\ts_waitcnt vmcnt(0)"
                 : "=&v"(a) : "v"(p) : "memory");
    if (__float_as_uint(a.y) == FLAGB && __float_as_uint(a.w) == FLAGB) return a;
  }
}

__device__ __forceinline__ void stage1024(const float2* base, float* dst, int tid) {
  float4 a = poll16(base + 2 * tid);
  ((float2*)dst)[tid] = make_float2(a.x, a.z);
  __syncthreads();
}

// canonical wave64 DPP sum: quad_perm xor1/xor2, row_shr 4/8, row_bcast 15/31.
// Result valid in lane 63 ONLY. VALU-speed (no LDS crosslane).
__device__ __forceinline__ float dpp_sum64(float x) {
  x += __int_as_float(__builtin_amdgcn_update_dpp(0, __float_as_int(x), 0xB1,  0xf, 0xf, true));
  x += __int_as_float(__builtin_amdgcn_update_dpp(0, __float_as_int(x), 0x4E,  0xf, 0xf, true));
  x += __int_as_float(__builtin_amdgcn_update_dpp(0, __float_as_int(x), 0x114, 0xf, 0xf, true));
  x += __int_as_float(__builtin_amdgcn_update_dpp(0, __float_as_int(x), 0x118, 0xf, 0xf, true));
  x += __int_as_float(__builtin_amdgcn_update_dpp(0, __float_as_int(x), 0x142, 0xa, 0xf, true));
  x += __int_as_float(__builtin_amdgcn_update_dpp(0, __float_as_int(x), 0x143, 0xc, 0xf, true));
  return x;
}

// ---------------- input-side GEMM: gather + K-split half, single bias -------
__device__ __forceinline__ void gemm_gather_body(const float* __restrict__ W,
                                                 const float* __restrict__ emb,
                                                 const int* __restrict__ word, int dec_mode,
                                                 const float* __restrict__ bias,
                                                 float* __restrict__ out, int rbase, int kbase) {
  __shared__ float xs[64][68];
  __shared__ float wsh[64][68];
  const int tid = threadIdx.x;
  const int a = tid >> 4;
  const int b = tid & 15;
  const int sr = tid & 63;
  const int kq = (tid >> 6) << 4;
  const int tok = dec_mode ? ((sr == 0) ? 0 : word[sr - 1]) : word[sr];
  const float* xrow = emb + (size_t)tok * 1024;
  float acc[4][4];
#pragma unroll
  for (int i = 0; i < 4; ++i)
#pragma unroll
    for (int q = 0; q < 4; ++q) acc[i][q] = 0.f;

  for (int kc = kbase; kc < kbase + 512; kc += 64) {
    const float4* gx = (const float4*)(xrow + kc + kq);
    const float4* gw = (const float4*)(W + (size_t)(rbase + sr) * 1024 + kc + kq);
    float4 vx0 = gx[0], vx1 = gx[1], vx2 = gx[2], vx3 = gx[3];
    float4 vw0 = gw[0], vw1 = gw[1], vw2 = gw[2], vw3 = gw[3];
    if (dec_mode) {
      vx0.x = fmaxf(vx0.x, 0.f); vx0.y = fmaxf(vx0.y, 0.f); vx0.z = fmaxf(vx0.z, 0.f); vx0.w = fmaxf(vx0.w, 0.f);
      vx1.x = fmaxf(vx1.x, 0.f); vx1.y = fmaxf(vx1.y, 0.f); vx1.z = fmaxf(vx1.z, 0.f); vx1.w = fmaxf(vx1.w, 0.f);
      vx2.x = fmaxf(vx2.x, 0.f); vx2.y = fmaxf(vx2.y, 0.f); vx2.z = fmaxf(vx2.z, 0.f); vx2.w = fmaxf(vx2.w, 0.f);
      vx3.x = fmaxf(vx3.x, 0.f); vx3.y = fmaxf(vx3.y, 0.f); vx3.z = fmaxf(vx3.z, 0.f); vx3.w = fmaxf(vx3.w, 0.f);
    }
    __syncthreads();
    xs[kq +  0][sr] = vx0.x; xs[kq +  1][sr] = vx0.y; xs[kq +  2][sr] = vx0.z; xs[kq +  3][sr] = vx0.w;
    xs[kq +  4][sr] = vx1.x; xs[kq +  5][sr] = vx1.y; xs[kq +  6][sr] = vx1.z; xs[kq +  7][sr] = vx1.w;
    xs[kq +  8][sr] = vx2.x; xs[kq +  9][sr] = vx2.y; xs[kq + 10][sr] = vx2.z; xs[kq + 11][sr] = vx2.w;
    xs[kq + 12][sr] = vx3.x; xs[kq + 13][sr] = vx3.y; xs[kq + 14][sr] = vx3.z; xs[kq + 15][sr] = vx3.w;
    wsh[kq +  0][sr] = vw0.x; wsh[kq +  1][sr] = vw0.y; wsh[kq +  2][sr] = vw0.z; wsh[kq +  3][sr] = vw0.w;
    wsh[kq +  4][sr] = vw1.x; wsh[kq +  5][sr] = vw1.y; wsh[kq +  6][sr] = vw1.z; wsh[kq +  7][sr] = vw1.w;
    wsh[kq +  8][sr] = vw2.x; wsh[kq +  9][sr] = vw2.y; wsh[kq + 10][sr] = vw2.z; wsh[kq + 11][sr] = vw2.w;
    wsh[kq + 12][sr] = vw3.x; wsh[kq + 13][sr] = vw3.y; wsh[kq + 14][sr] = vw3.z; wsh[kq + 15][sr] = vw3.w;
    __syncthreads();
#pragma unroll 8
    for (int kk = 0; kk < 64; ++kk) {
      float4 xv = *(const float4*)&xs[kk][a * 4];
      float4 wv = *(const float4*)&wsh[kk][b * 4];
      acc[0][0] = fmaf(xv.x, wv.x, acc[0][0]); acc[0][1] = fmaf(xv.x, wv.y, acc[0][1]);
      acc[0][2] = fmaf(xv.x, wv.z, acc[0][2]); acc[0][3] = fmaf(xv.x, wv.w, acc[0][3]);
      acc[1][0] = fmaf(xv.y, wv.x, acc[1][0]); acc[1][1] = fmaf(xv.y, wv.y, acc[1][1]);
      acc[1][2] = fmaf(xv.y, wv.z, acc[1][2]); acc[1][3] = fmaf(xv.y, wv.w, acc[1][3]);
      acc[2][0] = fmaf(xv.z, wv.x, acc[2][0]); acc[2][1] = fmaf(xv.z, wv.y, acc[2][1]);
      acc[2][2] = fmaf(xv.z, wv.z, acc[2][2]); acc[2][3] = fmaf(xv.z, wv.w, acc[2][3]);
      acc[3][0] = fmaf(xv.w, wv.x, acc[3][0]); acc[3][1] = fmaf(xv.w, wv.y, acc[3][1]);
      acc[3][2] = fmaf(xv.w, wv.z, acc[3][2]); acc[3][3] = fmaf(xv.w, wv.w, acc[3][3]);
    }
  }
  const int rb = rbase + b * 4;
  float4 bv = *(const float4*)(bias + rb);
#pragma unroll
  for (int i = 0; i < 4; ++i) {
    int t = a * 4 + i;
    float4 o;
    o.x = acc[i][0] + bv.x; o.y = acc[i][1] + bv.y;
    o.z = acc[i][2] + bv.z; o.w = acc[i][3] + bv.w;
    *(float4*)(out + (size_t)t * 4096 + rb) = o;
  }
}

// 256 blocks: quad 0/1 = enc K-half 0/1, quad 2/3 = dec K-half 0/1.
__global__ __launch_bounds__(256, 2) void gemm_dual_kernel(
    const int* __restrict__ tense, const float* __restrict__ tense_emb,
    const float* __restrict__ enc_emb, const float* __restrict__ dec_emb,
    const int* __restrict__ word,
    const float* __restrict__ enc_Wih, const float* __restrict__ enc_bih,
    const float* __restrict__ enc_bhh,
    const float* __restrict__ dec_Wih, const float* __restrict__ dec_bih,
    const float* __restrict__ dec_bhh,
    float* __restrict__ ws) {
  // distributed mailbox/tense init
  {
    int gid = blockIdx.x * blockDim.x + threadIdx.x;
    int gsz = gridDim.x * blockDim.x;
    int tens = tense[0];
    if (gid < 32) ws[OFF_TEN + gid] = tense_emb[tens * 32 + gid];
    float2* mb = (float2*)(ws + OFF_MB);
    for (int i = gid; i < (int)MB_PAIRS; i += gsz) {
      float2 v;
      if (i < (int)MB_H_PAIRS && (i >> 10) == 0) {
        int j = i & 1023;
        v.x = (j < Hd - 32) ? 0.f : tense_emb[tens * 32 + (j - (Hd - 32))];
        v.y = 1.0f;
      } else { v.x = 0.f; v.y = 0.f; }
      mb[i] = v;
    }
  }
  const int quad = blockIdx.x >> 6;
  const int rbase = (blockIdx.x & 63) * 64;
  if (quad == 0)
    gemm_gather_body(enc_Wih, enc_emb, word, 0, enc_bih, ws + OFF_GENC0, rbase, 0);
  else if (quad == 1)
    gemm_gather_body(enc_Wih, enc_emb, word, 0, enc_bhh, ws + OFF_GENC1, rbase, 512);
  else if (quad == 2)
    gemm_gather_body(dec_Wih, dec_emb, word, 1, dec_bih, ws + OFF_GDEC0, rbase, 0);
  else
    gemm_gather_body(dec_Wih, dec_emb, word, 1, dec_bhh, ws + OFF_GDEC1, rbase, 512);
}

// ---------------- W_out GEMM with fused per-row partial stats (R11-proven) --
__global__ __launch_bounds__(256, 2) void gemm_kernel(const float* __restrict__ W,
                                                      const float* __restrict__ x,
                                                      const float* __restrict__ bias,
                                                      float* __restrict__ out, int R,
                                                      float* __restrict__ sd) {
  __shared__ float xs[64][68];
  __shared__ float wsh[64][68];
  const int tid = threadIdx.x;
  const int a = tid >> 4;
  const int b = tid & 15;
  const int sr = tid & 63;
  const int kq = (tid >> 6) << 4;
  const int rbase = blockIdx.x * 64;
  float acc[4][4];
#pragma unroll
  for (int i = 0; i < 4; ++i)
#pragma unroll
    for (int q = 0; q < 4; ++q) acc[i][q] = 0.f;

  for (int kc = 0; kc < 1024; kc += 64) {
    const float4* gx = (const float4*)(x + (size_t)sr * 1024 + kc + kq);
    const float4* gw = (const float4*)(W + (size_t)(rbase + sr) * 1024 + kc + kq);
    float4 vx0 = gx[0], vx1 = gx[1], vx2 = gx[2], vx3 = gx[3];
    float4 vw0 = gw[0], vw1 = gw[1], vw2 = gw[2], vw3 = gw[3];
    __syncthreads();
    xs[kq +  0][sr] = vx0.x; xs[kq +  1][sr] = vx0.y; xs[kq +  2][sr] = vx0.z; xs[kq +  3][sr] = vx0.w;
    xs[kq +  4][sr] = vx1.x; xs[kq +  5][sr] = vx1.y; xs[kq +  6][sr] = vx1.z; xs[kq +  7][sr] = vx1.w;
    xs[kq +  8][sr] = vx2.x; xs[kq +  9][sr] = vx2.y; xs[kq + 10][sr] = vx2.z; xs[kq + 11][sr] = vx2.w;
    xs[kq + 12][sr] = vx3.x; xs[kq + 13][sr] = vx3.y; xs[kq + 14][sr] = vx3.z; xs[kq + 15][sr] = vx3.w;
    wsh[kq +  0][sr] = vw0.x; wsh[kq +  1][sr] = vw0.y; wsh[kq +  2][sr] = vw0.z; wsh[kq +  3][sr] = vw0.w;
    wsh[kq +  4][sr] = vw1.x; wsh[kq +  5][sr] = vw1.y; wsh[kq +  6][sr] = vw1.z; wsh[kq +  7][sr] = vw1.w;
    wsh[kq +  8][sr] = vw2.x; wsh[kq +  9][sr] = vw2.y; wsh[kq + 10][sr] = vw2.z; wsh[kq + 11][sr] = vw2.w;
    wsh[kq + 12][sr] = vw3.x; wsh[kq + 13][sr] = vw3.y; wsh[kq + 14][sr] = vw3.z; wsh[kq + 15][sr] = vw3.w;
    __syncthreads();
#pragma unroll 8
    for (int kk = 0; kk < 64; ++kk) {
      float4 xv = *(const float4*)&xs[kk][a * 4];
      float4 wv = *(const float4*)&wsh[kk][b * 4];
      acc[0][0] = fmaf(xv.x, wv.x, acc[0][0]); acc[0][1] = fmaf(xv.x, wv.y, acc[0][1]);
      acc[0][2] = fmaf(xv.x, wv.z, acc[0][2]); acc[0][3] = fmaf(xv.x, wv.w, acc[0][3]);
      acc[1][0] = fmaf(xv.y, wv.x, acc[1][0]); acc[1][1] = fmaf(xv.y, wv.y, acc[1][1]);
      acc[1][2] = fmaf(xv.y, wv.z, acc[1][2]); acc[1][3] = fmaf(xv.y, wv.w, acc[1][3]);
      acc[2][0] = fmaf(xv.z, wv.x, acc[2][0]); acc[2][1] = fmaf(xv.z, wv.y, acc[2][1]);
      acc[2][2] = fmaf(xv.z, wv.z, acc[2][2]); acc[2][3] = fmaf(xv.z, wv.w, acc[2][3]);
      acc[3][0] = fmaf(xv.w, wv.x, acc[3][0]); acc[3][1] = fmaf(xv.w, wv.y, acc[3][1]);
      acc[3][2] = fmaf(xv.w, wv.z, acc[3][2]); acc[3][3] = fmaf(xv.w, wv.w, acc[3][3]);
    }
  }
  const int rb = rbase + b * 4;
  float4 bv = *(const float4*)(bias + rb);
#pragma unroll
  for (int i = 0; i < 4; ++i) {
    int t = a * 4 + i;
    float4 o;
    o.x = acc[i][0] + bv.x; o.y = acc[i][1] + bv.y;
    o.z = acc[i][2] + bv.z; o.w = acc[i][3] + bv.w;
    *(float4*)(out + (size_t)t * R + rb) = o;
    float m = o.x; int mi = rb;
    if (o.y > m) { m = o.y; mi = rb + 1; }
    if (o.z > m) { m = o.z; mi = rb + 2; }
    if (o.w > m) { m = o.w; mi = rb + 3; }
    float s = __expf(o.x - m) + __expf(o.y - m) + __expf(o.z - m) + __expf(o.w - m);
#pragma unroll
    for (int off = 1; off < 16; off <<= 1) {
      float om = __shfl_xor(m, off, 64);
      int   oi = __shfl_xor(mi, off, 64);
      float os = __shfl_xor(s, off, 64);
      if (om > m || (om == m && oi < mi)) {
        s = os + s * __expf(m - om);
        m = om; mi = oi;
      } else {
        s = s + os * __expf(om - m);
      }
    }
    if (b == 0) {
      float* p = sd + ((size_t)t * 500 + blockIdx.x) * 4;
      p[0] = m; p[1] = (float)mi; p[2] = s;
    }
  }
}

// 16 scalar weight loads (stride 256B) via one opaque asm block
__device__ __forceinline__ void gload16(const float* base, float* d) {
  asm volatile(
      "global_load_dword %0, %16, off\n\t"
      "global_load_dword %1, %16, off offset:256\n\t"
      "global_load_dword %2, %16, off offset:512\n\t"
      "global_load_dword %3, %16, off offset:768\n\t"
      "global_load_dword %4, %16, off offset:1024\n\t"
      "global_load_dword %5, %16, off offset:1280\n\t"
      "global_load_dword %6, %16, off offset:1536\n\t"
      "global_load_dword %7, %16, off offset:1792\n\t"
      "global_load_dword %8, %16, off offset:2048\n\t"
      "global_load_dword %9, %16, off offset:2304\n\t"
      "global_load_dword %10, %16, off offset:2560\n\t"
      "global_load_dword %11, %16, off offset:2816\n\t"
      "global_load_dword %12, %16, off offset:3072\n\t"
      "global_load_dword %13, %16, off offset:3328\n\t"
      "global_load_dword %14, %16, off offset:3584\n\t"
      "global_load_dword %15, %16, off offset:3840\n\t"
      "s_waitcnt vmcnt(0)"
      : "=&v"(d[0]), "=&v"(d[1]), "=&v"(d[2]), "=&v"(d[3]),
        "=&v"(d[4]), "=&v"(d[5]), "=&v"(d[6]), "=&v"(d[7]),
        "=&v"(d[8]), "=&v"(d[9]), "=&v"(d[10]), "=&v"(d[11]),
        "=&v"(d[12]), "=&v"(d[13]), "=&v"(d[14]), "=&v"(d[15])
      : "v"(base));
}

// ---------------- persistent dataflow sequential kernel ---------------------
// R11 structure; gate reduction now DPP (result lane 63), split-G bias adds.
__global__ __launch_bounds__(512, 2) void seq_kernel(
    const float* __restrict__ enc_Whh, const float* __restrict__ dec_Whh,
    const float* __restrict__ W_mean, const float* __restrict__ b_mean,
    const float* __restrict__ W_var, const float* __restrict__ b_var,
    const float* __restrict__ W_l2h, const float* __restrict__ b_l2h,
    const float* __restrict__ eps, float* __restrict__ ws, float* __restrict__ dout) {
  __shared__ float hsbuf[2][Hd];
  __shared__ float lat[288];
  const int tid = threadIdx.x;
  const int lane = tid & 63;
  const int wid = tid >> 6;
  const int j = blockIdx.x * 8 + wid;          // 0..1023

  float2* mb = (float2*)(ws + OFF_MB);
  unsigned long long* mbq = (unsigned long long*)(ws + OFF_MB);
  const float* Ge0 = ws + OFF_GENC0;
  const float* Ge1 = ws + OFF_GENC1;
  const float* Gd0 = ws + OFF_GDEC0;
  const float* Gd1 = ws + OFF_GDEC1;
  float* h_all = ws + OFF_HALL;

  float we[4][16], wd[4][16];
#pragma unroll
  for (int r = 0; r < 4; ++r) {
    const size_t ro = (size_t)(r * Hd + j) * Hd + lane;
    gload16(enc_Whh + ro, we[r]);
    gload16(dec_Whh + ro, wd[r]);
  }

  // ---- encoder ----
  float c_reg = 0.f;
  float ga0 = Ge0[j], ga1 = Ge0[1024 + j], ga2 = Ge0[2048 + j], ga3 = Ge0[3072 + j];
  float gb0 = Ge1[j], gb1 = Ge1[1024 + j], gb2 = Ge1[2048 + j], gb3 = Ge1[3072 + j];
  for (int t = 0; t < Td; ++t) {
    stage1024(mb + (size_t)t * 1024, hsbuf[t & 1], tid);
    const float* hs = hsbuf[t & 1];
    float p0 = 0.f, p1 = 0.f, p2 = 0.f, p3 = 0.f;
#pragma unroll
    for (int i = 0; i < 16; ++i) {
      float hv = hs[lane + 64 * i];
      p0 = fmaf(we[0][i], hv, p0);
      p1 = fmaf(we[1][i], hv, p1);
      p2 = fmaf(we[2][i], hv, p2);
      p3 = fmaf(we[3][i], hv, p3);
    }
    p0 = dpp_sum64(p0); p1 = dpp_sum64(p1);
    p2 = dpp_sum64(p2); p3 = dpp_sum64(p3);
    float gi = ga0 + gb0 + p0, gf = ga1 + gb1 + p1;
    float gg = ga2 + gb2 + p2, go = ga3 + gb3 + p3;
    c_reg = fsigm(gf) * c_reg + fsigm(gi) * ftanh(gg);
    float hval = fsigm(go) * ftanh(c_reg);
    if (lane == 63) st_flag(mbq + (size_t)(t + 1) * 1024 + j, hval);
    if (t + 1 < Td) {
      ga0 = Ge0[(t + 1) * 4096 + j]; ga1 = Ge0[(t + 1) * 4096 + 1024 + j];
      ga2 = Ge0[(t + 1) * 4096 + 2048 + j]; ga3 = Ge0[(t + 1) * 4096 + 3072 + j];
      gb0 = Ge1[(t + 1) * 4096 + j]; gb1 = Ge1[(t + 1) * 4096 + 1024 + j];
      gb2 = Ge1[(t + 1) * 4096 + 2048 + j]; gb3 = Ge1[(t + 1) * 4096 + 3072 + j];
    }
  }

  // ---- mean/logvar + latent (blocks 0..31; proven shfl path) ----
  if (j < 256) {
    stage1024(mb + (size_t)Td * 1024, hsbuf[0], tid);
    const float* hs = hsbuf[0];
    const float* Wm = W_mean + (size_t)j * Hd;
    const float* Wv = W_var + (size_t)j * Hd;
    float pm = 0.f, pv = 0.f;
#pragma unroll
    for (int i = 0; i < 16; ++i) {
      float hv = hs[lane + 64 * i];
      pm = fmaf(Wm[lane + 64 * i], hv, pm);
      pv = fmaf(Wv[lane + 64 * i], hv, pv);
    }
#pragma unroll
    for (int off = 32; off; off >>= 1) {
      pm += __shfl_xor(pm, off, 64); pv += __shfl_xor(pv, off, 64);
    }
    if (lane == 0) {
      float m = pm + b_mean[j];
      float lv = pv + b_var[j];
      dout[2048064 + j] = m;
      dout[2048320 + j] = lv;
      float latv = m + eps[j] * __expf(0.5f * lv);
      st_flag(mbq + MB_H_PAIRS + j, latv);
    }
  }

  // ---- poll latent, build [latent | tense] in LDS ----
  if (tid < 128) {
    float4 a = poll16(mb + MB_H_PAIRS + 2 * tid);
    lat[2 * tid] = a.x; lat[2 * tid + 1] = a.z;
  } else if (tid < 160) {
    lat[256 + (tid - 128)] = ws[OFF_TEN + (tid - 128)];
  }
  __syncthreads();

  // ---- dec_h0[j] = W_l2h[j]·[latent|tense] + b ----
  {
    const float* Wr = W_l2h + (size_t)j * 288;
    float p = fmaf(Wr[lane], lat[lane], 0.f);
    p = fmaf(Wr[lane + 64], lat[lane + 64], p);
    p = fmaf(Wr[lane + 128], lat[lane + 128], p);
    p = fmaf(Wr[lane + 192], lat[lane + 192], p);
    if (lane < 32) p = fmaf(Wr[lane + 256], lat[lane + 256], p);
#pragma unroll
    for (int off = 32; off; off >>= 1) p += __shfl_xor(p, off, 64);
    if (lane == 0) st_flag(mbq + (size_t)65 * 1024 + j, p + b_l2h[j]);
  }
  __syncthreads();

  // ---- decoder ----
  c_reg = 0.f;
  ga0 = Gd0[j]; ga1 = Gd0[1024 + j]; ga2 = Gd0[2048 + j]; ga3 = Gd0[3072 + j];
  gb0 = Gd1[j]; gb1 = Gd1[1024 + j]; gb2 = Gd1[2048 + j]; gb3 = Gd1[3072 + j];
  for (int t = 0; t < Td; ++t) {
    stage1024(mb + (size_t)(65 + t) * 1024, hsbuf[t & 1], tid);
    const float* hs = hsbuf[t & 1];
    float p0 = 0.f, p1 = 0.f, p2 = 0.f, p3 = 0.f;
#pragma unroll
    for (int i = 0; i < 16; ++i) {
      float hv = hs[lane + 64 * i];
      p0 = fmaf(wd[0][i], hv, p0);
      p1 = fmaf(wd[1][i], hv, p1);
      p2 = fmaf(wd[2][i], hv, p2);
      p3 = fmaf(wd[3][i], hv, p3);
    }
    p0 = dpp_sum64(p0); p1 = dpp_sum64(p1);
    p2 = dpp_sum64(p2); p3 = dpp_sum64(p3);
    float gi = ga0 + gb0 + p0, gf = ga1 + gb1 + p1;
    float gg = ga2 + gb2 + p2, go = ga3 + gb3 + p3;
    c_reg = fsigm(gf) * c_reg + fsigm(gi) * ftanh(gg);
    float hval = fsigm(go) * ftanh(c_reg);
    if (lane == 63) {
      if (t + 1 < Td) st_flag(mbq + (size_t)(66 + t) * 1024 + j, hval);
      h_all[(size_t)t * Hd + j] = hval;
    }
    if (t + 1 < Td) {
      ga0 = Gd0[(t + 1) * 4096 + j]; ga1 = Gd0[(t + 1) * 4096 + 1024 + j];
      ga2 = Gd0[(t + 1) * 4096 + 2048 + j]; ga3 = Gd0[(t + 1) * 4096 + 3072 + j];
      gb0 = Gd1[(t + 1) * 4096 + j]; gb1 = Gd1[(t + 1) * 4096 + 1024 + j];
      gb2 = Gd1[(t + 1) * 4096 + 2048 + j]; gb3 = Gd1[(t + 1) * 4096 + 3072 + j];
    }
  }
}

// ---------------- combine 500 partials + normalize quarter-row ---------------
__global__ __launch_bounds__(256) void lfin_kernel(float* __restrict__ out,
                                                   const float* __restrict__ sd) {
  const int blk = blockIdx.x, t = blk >> 2, q = blk & 3, tid = threadIdx.x;
  __shared__ float sm[256];
  __shared__ float ss[256];
  __shared__ int si[256];
  float M = -INFINITY, S = 0.f; int MI = 0x7fffffff;
  for (int k = tid; k < 500; k += 256) {
    const float* p = sd + ((size_t)t * 500 + k) * 4;
    float m = p[0]; int mi = (int)p[1]; float s = p[2];
    if (m > M || (m == M && mi < MI)) {
      S = s + S * __expf(M - m);
      M = m; MI = mi;
    } else {
      S = S + s * __expf(m - M);
    }
  }
  sm[tid] = M; si[tid] = MI; ss[tid] = S;
  __syncthreads();
  for (int st = 128; st > 0; st >>= 1) {
    if (tid < st) {
      float om = sm[tid + st]; int oi = si[tid + st]; float os = ss[tid + st];
      if (om > sm[tid] || (om == sm[tid] && oi < si[tid])) {
        ss[tid] = os + ss[tid] * __expf(sm[tid] - om);
        sm[tid] = om; si[tid] = oi;
      } else {
        ss[tid] = ss[tid] + os * __expf(om - sm[tid]);
      }
    }
    __syncthreads();
  }
  float corr = sm[0] + logf(ss[0]);
  float4* r4 = (float4*)(out + 64 + (size_t)t * Vd + q * 8000);
  for (int i = tid; i < 2000; i += 256) {
    float4 v = r4[i];
    v.x -= corr; v.y -= corr; v.z -= corr; v.w -= corr;
    r4[i] = v;
  }
  if (q == 0 && tid == 0) out[t] = (float)si[0];
}

extern "C" void kernel_launch(void* const* d_in, const int* in_sizes, int n_in,
                              void* d_out, int out_size, void* d_ws, size_t ws_size,
                              hipStream_t stream) {
  (void)in_sizes; (void)n_in; (void)out_size; (void)ws_size;
  const int* word       = (const int*)d_in[0];
  const int* tense      = (const int*)d_in[1];
  const float* tense_emb = (const float*)d_in[3];
  const float* enc_emb   = (const float*)d_in[4];
  const float* enc_Wih   = (const float*)d_in[5];
  const float* enc_Whh   = (const float*)d_in[6];
  const float* enc_bih   = (const float*)d_in[7];
  const float* enc_bhh   = (const float*)d_in[8];
  const float* W_mean    = (const float*)d_in[9];
  const float* b_mean    = (const float*)d_in[10];
  const float* W_var     = (const float*)d_in[11];
  const float* b_var     = (const float*)d_in[12];
  const float* W_l2h     = (const float*)d_in[13];
  const float* b_l2h     = (const float*)d_in[14];
  const float* dec_emb   = (const float*)d_in[15];
  const float* dec_Wih   = (const float*)d_in[16];
  const float* dec_Whh   = (const float*)d_in[17];
  const float* dec_bih   = (const float*)d_in[18];
  const float* dec_bhh   = (const float*)d_in[19];
  const float* W_out     = (const float*)d_in[20];
  const float* b_out     = (const float*)d_in[21];
  const float* eps       = (const float*)d_in[22];
  float* out = (float*)d_out;
  float* ws  = (float*)d_ws;

  gemm_dual_kernel<<<256, 256, 0, stream>>>(tense, tense_emb, enc_emb, dec_emb, word,
                                            enc_Wih, enc_bih, enc_bhh,
                                            dec_Wih, dec_bih, dec_bhh, ws);
  seq_kernel<<<128, 512, 0, stream>>>(enc_Whh, dec_Whh, W_mean, b_mean, W_var, b_var,
                                      W_l2h, b_l2h, eps, ws, out);
  gemm_kernel<<<500, 256, 0, stream>>>(W_out, ws + OFF_HALL, b_out, out + 64, 32000,
                                       ws + OFF_ST2);
  lfin_kernel<<<256, 256, 0, stream>>>(out, ws + OFF_ST2);
}